// Round 8
// baseline (274.021 us; speedup 1.0000x reference)
//
#include <hip/hip_runtime.h>
#include <hip/hip_bf16.h>
#include <math.h>

#define N_NODES 50000
#define N_EDGES 600000
#define DIM 128
#define KGAM 8
#define EPSV 1e-9f
#define RBLK 3128    // padded 16-row blocks in tiled A arrays (50048 rows)
#define NTILES 1564  // 32-row GEMM tiles

typedef __attribute__((ext_vector_type(8))) short short8;
typedef __attribute__((ext_vector_type(4))) float float4v;

__device__ __forceinline__ short f2bf(float f) {
    return (short)__builtin_bit_cast(unsigned short, __float2bfloat16(f));
}
__device__ __forceinline__ unsigned int pack2(float a, float b) {
    return (unsigned int)(unsigned short)f2bf(a) | ((unsigned int)(unsigned short)f2bf(b) << 16);
}
__device__ __forceinline__ float sigm(float x) { return 1.f / (1.f + __expf(-x)); }

// ---------------- CSR build ----------------
__global__ void k_deg(const int* __restrict__ dst, int* __restrict__ deg) {
    int e = blockIdx.x * blockDim.x + threadIdx.x;
    if (e < N_EDGES) atomicAdd(&deg[dst[e]], 1);
}

__global__ void k_scan1(const int* __restrict__ deg, int* __restrict__ rowstart,
                        int* __restrict__ bsums, float* __restrict__ norm) {
    __shared__ int s[256];
    int tid = threadIdx.x;
    int i0 = blockIdx.x * 1024 + tid * 4;
    int v[4]; int sum = 0;
#pragma unroll
    for (int c = 0; c < 4; ++c) {
        int i = i0 + c;
        int d = (i < N_NODES) ? deg[i] : 0;
        v[c] = d; sum += d;
    }
    s[tid] = sum; __syncthreads();
#pragma unroll
    for (int off = 1; off < 256; off <<= 1) {
        int t = (tid >= off) ? s[tid - off] : 0;
        __syncthreads();
        s[tid] += t;
        __syncthreads();
    }
    if (tid == 255) bsums[blockIdx.x] = s[255];
    int run = s[tid] - sum;
#pragma unroll
    for (int c = 0; c < 4; ++c) {
        int i = i0 + c;
        if (i < N_NODES) {
            rowstart[i] = run;
            norm[i] = rsqrtf((float)(v[c] < 1 ? 1 : v[c]));
        }
        run += v[c];
    }
}

__global__ void k_scan2(int* __restrict__ bsums, int nb) {
    __shared__ int s[64];
    int tid = threadIdx.x;
    int v = (tid < nb) ? bsums[tid] : 0;
    s[tid] = v; __syncthreads();
#pragma unroll
    for (int off = 1; off < 64; off <<= 1) {
        int t = (tid >= off) ? s[tid - off] : 0;
        __syncthreads();
        s[tid] += t;
        __syncthreads();
    }
    if (tid < nb) bsums[tid] = s[tid] - v;
}

__global__ void k_scan3(const int* __restrict__ bsums, int* __restrict__ rowstart) {
    int i = blockIdx.x * blockDim.x + threadIdx.x;
    if (i < N_NODES) rowstart[i] += bsums[i >> 10];
    if (i == 0) rowstart[N_NODES] = N_EDGES;
}

__global__ void k_fill(const int* __restrict__ src, const int* __restrict__ dst,
                       const int* __restrict__ rowstart, int* __restrict__ cnt,
                       int* __restrict__ esrc) {
    int e = blockIdx.x * blockDim.x + threadIdx.x;
    if (e < N_EDGES) {
        int d = dst[e];
        int slot = rowstart[d] + atomicAdd(&cnt[d], 1);
        esrc[slot] = src[e];
    }
}

// ------------- weights: 6 coefficient-folded bf16 matrices (coeffs inlined) -------
__global__ void k_wconv(const float* __restrict__ W0, const float* __restrict__ W1,
                        const float* __restrict__ W2, const float* __restrict__ gl,
                        const float* __restrict__ gh, const float* __restrict__ gm,
                        unsigned int* __restrict__ Wb) {
    int g = blockIdx.y;
    float a0 = 0, b0 = 0, a1 = 0, b1 = 0, sg = 0, m2 = 0;
#pragma unroll
    for (int k = 0; k < KGAM; ++k) {
        float al = EPSV + (float)k * (1.f - 2.f * EPSV) / (KGAM - 1);
        float md = EPSV + (float)k * (1.f - EPSV) / (KGAM - 1);
        float l = fmaxf(gl[k], 0.f), h = fmaxf(gh[k], 0.f), m = fmaxf(gm[k], 0.f);
        a0 += al * l;  b0 += (1.f - al) * l;
        a1 += -al * h; b1 += (1.f - al) * h;
        sg += m;       m2 += md * m;
    }
    float cc[6] = {a0, b0, a1, b1, sg, -m2};
    float c = cc[g];
    const float* Ws = (g < 2) ? W0 : (g < 4) ? W1 : W2;
    int i = (blockIdx.x * 256 + threadIdx.x) * 4;
    if (i < DIM * DIM) {
        float4 v = *(const float4*)(Ws + i);
        uint2 o; o.x = pack2(c * v.x, c * v.y); o.y = pack2(c * v.z, c * v.w);
        *(uint2*)(Wb + (g * DIM * DIM + i) / 2) = o;
    }
}

// tiled A-layout short-offset for (row, k)
__device__ __forceinline__ size_t tiled_off(int row, int k) {
    return (size_t)(row >> 4) * 2048 + ((k >> 5) << 9) + (((k >> 3) & 3) << 7)
         + ((row & 15) << 3) + (k & 7);
}

// -------- prescale: fb = bf16(feature) [tiled], fp = bf16(feature*norm) [row-major]
__global__ void k_prescale(const float4* __restrict__ f, const float* __restrict__ norm,
                           unsigned int* __restrict__ fb, uint2* __restrict__ fp) {
    int i = blockIdx.x * 256 + threadIdx.x;
    if (i >= N_NODES * DIM / 4) return;
    int row = i >> 5;
    int k0 = (i & 31) * 4;
    float nv = norm[row];
    float4 v = f[i];
    uint2 a; a.x = pack2(v.x, v.y); a.y = pack2(v.z, v.w);
    uint2 b; b.x = pack2(v.x * nv, v.y * nv); b.y = pack2(v.z * nv, v.w * nv);
    *(uint2*)(fb + tiled_off(row, k0) / 2) = a;
    fp[i] = b;
}

// ------- SpMM: ONE node per wave, 4 edges in parallel (4 groups x 16 lanes) -------
// Each group handles every 4th edge; pair-unrolled (8 gathers in flight per wave);
// cross-group reduce via shfl_xor(16/32). Eliminates the max-over-4-nodes
// divergence of the previous 4-nodes/wave scheme.
__device__ __forceinline__ void acc8(float* a, uint4 r) {
    a[0] += __builtin_bit_cast(float, r.x << 16);
    a[1] += __builtin_bit_cast(float, r.x & 0xffff0000u);
    a[2] += __builtin_bit_cast(float, r.y << 16);
    a[3] += __builtin_bit_cast(float, r.y & 0xffff0000u);
    a[4] += __builtin_bit_cast(float, r.z << 16);
    a[5] += __builtin_bit_cast(float, r.z & 0xffff0000u);
    a[6] += __builtin_bit_cast(float, r.w << 16);
    a[7] += __builtin_bit_cast(float, r.w & 0xffff0000u);
}

__global__ void k_spmm(const uint4* __restrict__ in, const float* __restrict__ norm,
                       const int* __restrict__ rowstart, const int* __restrict__ esrc,
                       uint4* __restrict__ hout, uint4* __restrict__ preout, int wpre) {
    int v = blockIdx.x * 4 + (threadIdx.x >> 6);
    if (v >= N_NODES) return;
    int lane = threadIdx.x & 63;
    int eg = lane >> 4;        // edge group 0..3
    int l = lane & 15;         // 16B chunk within row
    int beg = rowstart[v], end = rowstart[v + 1];
    float a[8] = {0.f, 0.f, 0.f, 0.f, 0.f, 0.f, 0.f, 0.f};
    int e = beg + eg;
    for (; e + 4 < end; e += 8) {
        int u0 = esrc[e], u1 = esrc[e + 4];
        uint4 r0 = in[(size_t)u0 * 16 + l];
        uint4 r1 = in[(size_t)u1 * 16 + l];
        acc8(a, r0); acc8(a, r1);
    }
    if (e < end) {
        uint4 r = in[(size_t)esrc[e] * 16 + l];
        acc8(a, r);
    }
    // reduce across the 4 edge groups
#pragma unroll
    for (int j = 0; j < 8; ++j) {
        a[j] += __shfl_xor(a[j], 16, 64);
        a[j] += __shfl_xor(a[j], 32, 64);
    }
    if (eg == 0) {
        float nv = norm[v];
        uint4 o;
        o.x = pack2(a[0] * nv, a[1] * nv); o.y = pack2(a[2] * nv, a[3] * nv);
        o.z = pack2(a[4] * nv, a[5] * nv); o.w = pack2(a[6] * nv, a[7] * nv);
        size_t tix = (size_t)(v >> 4) * 256 + (size_t)(l >> 2) * 64
                   + (size_t)(l & 3) * 16 + (v & 15);
        hout[tix] = o;
        if (wpre) {
            float n2 = nv * nv;
            uint4 p;
            p.x = pack2(a[0] * n2, a[1] * n2); p.y = pack2(a[2] * n2, a[3] * n2);
            p.z = pack2(a[4] * n2, a[5] * n2); p.w = pack2(a[6] * n2, a[7] * n2);
            preout[(size_t)v * 16 + l] = p;
        }
    }
}

// ------- fused tri-GEMM: small oversubscribed blocks (256 thr, 32 rows, 24KB LDS) --
// 1564 blocks, ~4 resident/CU, ~6 generations: blocks naturally phase-stagger so
// one block's DMA-drain barrier overlaps another's MFMA. Slice s = g*8+rb*4+ks,
// contiguous 1KB in tiled A arrays. Wave wv computes col-tiles 2wv, 2wv+1.
// A: lane holds A[m=lane&15][k=quad*8+j]; B: W[n=lane&15][k=quad*8+j];
// C/D: col=lane&15, row=quad*4+reg (verified R2-R7)
typedef const __attribute__((address_space(1))) unsigned int* gp1_t;
typedef __attribute__((address_space(3))) unsigned int* lp3_t;

__global__ __launch_bounds__(256, 4) void k_gemm_fused(
    const short* __restrict__ hB, const short* __restrict__ fB,
    const short* __restrict__ h1B, const short* __restrict__ Wb,
    const float* __restrict__ bias, const float* __restrict__ snorm,
    float* __restrict__ out) {
    __shared__ short Ts[24 * 512];   // 24 KB

    const int tid = threadIdx.x;
    const int lane = tid & 63;
    const int wv = tid >> 6;         // 0..3
    const int m = lane & 15;
    const int quad = lane >> 4;
    const int r0 = blockIdx.x * 32;

    // stage: wave wv issues slices wv*6 .. wv*6+5 (each contiguous 1KB)
#pragma unroll
    for (int i = 0; i < 6; ++i) {
        int s = wv * 6 + i;                  // s = g*8 + rb*4 + ks
        int g = s >> 3, rb = (s >> 2) & 1, ks = s & 3;
        const short* base = (g == 0) ? hB : (g == 1) ? fB : h1B;
        const short* gp = base + (size_t)(blockIdx.x * 2 + rb) * 2048 + ks * 512 + lane * 8;
        __builtin_amdgcn_global_load_lds((gp1_t)(const void*)gp,
                                         (lp3_t)(void*)&Ts[s * 512], 16, 0, 0);
    }
    __syncthreads();

    float4v acc[3][2][2];   // [g][rb][c]
    const float4v zero = {0.f, 0.f, 0.f, 0.f};
#pragma unroll
    for (int g = 0; g < 3; ++g)
#pragma unroll
        for (int rb = 0; rb < 2; ++rb) {
            acc[g][rb][0] = zero; acc[g][rb][1] = zero;
        }

#pragma unroll
    for (int ks = 0; ks < 4; ++ks) {
        short8 xh[2], xf[2], x1[2];
#pragma unroll
        for (int rb = 0; rb < 2; ++rb) {
            const short* ap = &Ts[(rb * 4 + ks) * 512 + lane * 8];
            xh[rb] = *(const short8*)(ap);
            xf[rb] = *(const short8*)(ap + 8 * 512);
            x1[rb] = *(const short8*)(ap + 16 * 512);
        }
#pragma unroll
        for (int c = 0; c < 2; ++c) {
            const short* wk = Wb + (size_t)((wv * 2 + c) * 16 + m) * DIM + quad * 8 + ks * 32;
            short8 b0 = *(const short8*)(wk);
            short8 b1 = *(const short8*)(wk + DIM * DIM);
            short8 b2 = *(const short8*)(wk + 2 * DIM * DIM);
            short8 b3 = *(const short8*)(wk + 3 * DIM * DIM);
            short8 b4 = *(const short8*)(wk + 4 * DIM * DIM);
            short8 b5 = *(const short8*)(wk + 5 * DIM * DIM);
#pragma unroll
            for (int rb = 0; rb < 2; ++rb) {
                acc[0][rb][c] = __builtin_amdgcn_mfma_f32_16x16x32_bf16(xh[rb], b0, acc[0][rb][c], 0, 0, 0);
                acc[0][rb][c] = __builtin_amdgcn_mfma_f32_16x16x32_bf16(xf[rb], b1, acc[0][rb][c], 0, 0, 0);
                acc[1][rb][c] = __builtin_amdgcn_mfma_f32_16x16x32_bf16(xh[rb], b2, acc[1][rb][c], 0, 0, 0);
                acc[1][rb][c] = __builtin_amdgcn_mfma_f32_16x16x32_bf16(xf[rb], b3, acc[1][rb][c], 0, 0, 0);
                acc[2][rb][c] = __builtin_amdgcn_mfma_f32_16x16x32_bf16(x1[rb], b4, acc[2][rb][c], 0, 0, 0);
                acc[2][rb][c] = __builtin_amdgcn_mfma_f32_16x16x32_bf16(xf[rb], b5, acc[2][rb][c], 0, 0, 0);
            }
        }
    }

    // epilogue: sequential mutual gating + bias + graph-norm + relu
#pragma unroll
    for (int rb = 0; rb < 2; ++rb) {
#pragma unroll
        for (int r = 0; r < 4; ++r) {
            int row = r0 + rb * 16 + quad * 4 + r;
            if (row < N_NODES) {
                float sn = snorm[row];
#pragma unroll
                for (int c = 0; c < 2; ++c) {
                    int col = (wv * 2 + c) * 16 + m;
                    float o0 = acc[0][rb][c][r], o1 = acc[1][rb][c][r], o2 = acc[2][rb][c][r];
                    float g0 = o0 * sigm(o1 + o2);
                    float g1 = o1 * sigm(g0 + o2);
                    float g2 = o2 * sigm(g0 + g1);
                    float vv = (g0 + g1 + g2 + bias[col]) * sn;
                    out[(size_t)row * DIM + col] = fmaxf(vv, 0.f);
                }
            }
        }
    }
}

extern "C" void kernel_launch(void* const* d_in, const int* in_sizes, int n_in,
                              void* d_out, int out_size, void* d_ws, size_t ws_size,
                              hipStream_t stream) {
    const float* feature = (const float*)d_in[0];
    const float* snorm   = (const float*)d_in[1];
    const int*   src     = (const int*)d_in[2];
    const int*   dst     = (const int*)d_in[3];
    const float* W_low   = (const float*)d_in[4];
    const float* W_high  = (const float*)d_in[5];
    const float* W_mid   = (const float*)d_in[6];
    const float* gl      = (const float*)d_in[7];
    const float* gh      = (const float*)d_in[8];
    const float* gm      = (const float*)d_in[9];
    const float* bias    = (const float*)d_in[10];
    float* out = (float*)d_out;

    char* w = (char*)d_ws;
    auto alloc = [&](size_t bytes) {
        char* p = w;
        w += (bytes + 255) & ~(size_t)255;
        return p;
    };
    const size_t tiledBytes = (size_t)RBLK * 2048 * 2;
    float* norm   = (float*)alloc((size_t)N_NODES * 4);
    int* deg      = (int*)alloc((size_t)2 * N_NODES * 4);
    int* cnt      = deg + N_NODES;
    int* rowstart = (int*)alloc((size_t)(N_NODES + 1) * 4);
    int* bsums    = (int*)alloc(64 * 4);
    int* esrc     = (int*)alloc((size_t)N_EDGES * 4);
    short* Wb     = (short*)alloc((size_t)6 * DIM * DIM * 2);
    short* fb     = (short*)alloc(tiledBytes);                    // tiled
    short* fp     = (short*)alloc((size_t)N_NODES * DIM * 2);     // row-major
    short* h      = (short*)alloc(tiledBytes);                    // tiled
    short* hp     = (short*)alloc((size_t)N_NODES * DIM * 2);     // row-major
    short* h1     = (short*)alloc(tiledBytes);                    // tiled

    hipMemsetAsync(deg, 0, (size_t)2 * N_NODES * 4, stream);
    k_deg<<<(N_EDGES + 255) / 256, 256, 0, stream>>>(dst, deg);
    int nchunks = (N_NODES + 1023) / 1024;  // 49
    k_scan1<<<nchunks, 256, 0, stream>>>(deg, rowstart, bsums, norm);
    k_scan2<<<1, 64, 0, stream>>>(bsums, nchunks);
    k_scan3<<<(N_NODES + 255) / 256, 256, 0, stream>>>(bsums, rowstart);
    k_fill<<<(N_EDGES + 255) / 256, 256, 0, stream>>>(src, dst, rowstart, cnt, esrc);
    k_wconv<<<dim3(16, 6), 256, 0, stream>>>(W_low, W_high, W_mid, gl, gh, gm,
                                             (unsigned int*)Wb);
    k_prescale<<<(N_NODES * DIM / 4 + 255) / 256, 256, 0, stream>>>(
        (const float4*)feature, norm, (unsigned int*)fb, (uint2*)fp);

    int spmm_blocks = (N_NODES + 3) / 4;   // one node per wave, 4 waves/block
    k_spmm<<<spmm_blocks, 256, 0, stream>>>((const uint4*)fp, norm, rowstart, esrc,
                                            (uint4*)h, (uint4*)hp, 1);
    k_spmm<<<spmm_blocks, 256, 0, stream>>>((const uint4*)hp, norm, rowstart, esrc,
                                            (uint4*)h1, (uint4*)hp, 0);

    k_gemm_fused<<<NTILES, 256, 0, stream>>>(h, fb, h1, Wb, bias, snorm, out);
}